// Round 2
// baseline (211.154 us; speedup 1.0000x reference)
//
#include <hip/hip_runtime.h>
#include <math.h>

// Literal per-element port of the reference (correctness probe).
// out flat layout: ((((o*8 + i)*128 + ic)*8 + j)*7 + u)*7 + v
// signal (= weight) flat: ((o*128 + ic)*8 + d)*49 + h*7 + w  (d = group, h = axis-3 k, w = axis-4 k)
// Mapping per reference:
//   d-coordinate:  tH = (theta_j - theta_i) mod 2pi, normalized by largest = 2pi*7/8 -> posD = (j-i) mod 8
//   spatial:       (rx, ry) = R(-theta_i) * (lin[u], lin[v]);  rx -> H axis (stride 7), ry -> W axis (stride 1)
//   trilinear with align_corners + zero padding (validity masked weights, clipped indices)

constexpr int BLOCK = 256;

__global__ __launch_bounds__(BLOCK)
void lift_literal(const float* __restrict__ sig, float* __restrict__ out, int total) {
  int f = blockIdx.x * BLOCK + threadIdx.x;
  if (f >= total) return;

  int vv = f % 7;
  int t1 = f / 7;
  int uu = t1 % 7;
  int t2 = t1 / 7;
  int j  = t2 % 8;
  int t3 = t2 / 8;
  int ic = t3 & 127;
  int t4 = t3 >> 7;
  int gi = t4 & 7;
  int o  = t4 >> 3;

  const float TWO_PI_F = 6.28318530717958647692f;   // rounds to f32 2*pi (0x40C90FDB)
  const float STEP = TWO_PI_F / 8.0f;               // exact /8 -> same bits as jnp's elems step

  float ti = (float)gi * STEP;
  float tj = (float)j  * STEP;

  // ---- D (group) coordinate ----
  float tH = fmodf(tj - ti, TWO_PI_F);
  if (tH < 0.0f) tH += TWO_PI_F;                    // python % semantics
  const float largest = TWO_PI_F * 7.0f / 8.0f;
  float cD = 2.0f * tH / largest - 1.0f;
  float posD = (cD + 1.0f) * 0.5f * 7.0f;
  float flD = floorf(posD);
  float fd  = posD - flD;
  int dlo = (int)flD, dhi = dlo + 1;
  float wd0 = (dlo >= 0 && dlo <= 7) ? (1.0f - fd) : 0.0f;
  float wd1 = (dhi >= 0 && dhi <= 7) ? fd : 0.0f;
  int d0 = min(max(dlo, 0), 7) * 49;
  int d1 = min(max(dhi, 0), 7) * 49;

  // ---- rotation by inverse(e_i): angle (-theta_i) mod 2pi ----
  float inv = fmodf(-ti, TWO_PI_F);
  if (inv < 0.0f) inv += TWO_PI_F;
  float cs = cosf(inv), sn = sinf(inv);

  float gx = (float)(uu - 3) * (1.0f / 3.0f);       // lin[u] (x)
  float gy = (float)(vv - 3) * (1.0f / 3.0f);       // lin[v] (y)
  float rx = cs * gx - sn * gy;
  float ry = sn * gx + cs * gy;

  // ---- H axis (rx) ----
  float posH = (rx + 1.0f) * 0.5f * 6.0f;
  float flH = floorf(posH);
  float fh  = posH - flH;
  int hlo = (int)flH, hhi = hlo + 1;
  float wh0 = (hlo >= 0 && hlo <= 6) ? (1.0f - fh) : 0.0f;
  float wh1 = (hhi >= 0 && hhi <= 6) ? fh : 0.0f;
  int h0 = min(max(hlo, 0), 6) * 7;
  int h1 = min(max(hhi, 0), 6) * 7;

  // ---- W axis (ry) ----
  float posW = (ry + 1.0f) * 0.5f * 6.0f;
  float flW = floorf(posW);
  float fw  = posW - flW;
  int wlo = (int)flW, whi = wlo + 1;
  float wq0 = (wlo >= 0 && wlo <= 6) ? (1.0f - fw) : 0.0f;
  float wq1 = (whi >= 0 && whi <= 6) ? fw : 0.0f;
  int q0 = min(max(wlo, 0), 6);
  int q1 = min(max(whi, 0), 6);

  const float* __restrict__ s = sig + (size_t)((o * 128 + ic) * 392);

  float a00 = wd0 * wh0, a01 = wd0 * wh1;
  float a10 = wd1 * wh0, a11 = wd1 * wh1;

  float acc = s[d0 + h0 + q0] * (a00 * wq0) + s[d0 + h0 + q1] * (a00 * wq1)
            + s[d0 + h1 + q0] * (a01 * wq0) + s[d0 + h1 + q1] * (a01 * wq1)
            + s[d1 + h0 + q0] * (a10 * wq0) + s[d1 + h0 + q1] * (a10 * wq1)
            + s[d1 + h1 + q0] * (a11 * wq0) + s[d1 + h1 + q1] * (a11 * wq1);

  out[f] = acc;
}

extern "C" void kernel_launch(void* const* d_in, const int* in_sizes, int n_in,
                              void* d_out, int out_size, void* d_ws, size_t ws_size,
                              hipStream_t stream) {
  const float* w = (const float*)d_in[0];
  float* out = (float*)d_out;
  int total = out_size;                       // 128*8*128*8*7*7 = 51,380,224
  int blocks = (total + BLOCK - 1) / BLOCK;   // 200,704
  hipLaunchKernelGGL(lift_literal, dim3(blocks), dim3(BLOCK), 0, stream, w, out, total);
}